// Round 7
// baseline (325.092 us; speedup 1.0000x reference)
//
#include <hip/hip_runtime.h>
#include <stdint.h>

// Problem constants
#define S_DIM 512
#define B_DIM 64
#define T_DIM 768
#define A_DIM 512
#define H1_DIM 768
#define H2_DIM 640
#define N_DIM (H1_DIM + H2_DIM)   // 1408 combined hidden cols
#define M_DIM (S_DIM * B_DIM)     // 32768 rows
#define K_DIM T_DIM               // 768
#define NSLOT 22                  // 11 n-tiles x 2 wave-columns

typedef short s16x8 __attribute__((ext_vector_type(8)));
typedef float f32x4 __attribute__((ext_vector_type(4)));

__device__ __forceinline__ unsigned short f2bf(float f) {
    unsigned u = __float_as_uint(f);
    u += 0x7fffu + ((u >> 16) & 1u);   // round-to-nearest-even
    return (unsigned short)(u >> 16);
}

// RNE pack of 2 fp32 -> 2 bf16 in one dword (lo = a, hi = b; == f2bf pair)
__device__ __forceinline__ unsigned pk2(float a, float b) {
    return (unsigned)f2bf(a) | ((unsigned)f2bf(b) << 16);
}

// --- prep: bias GEMV (blocked) | convW (LDS transpose) ---
// convA is GONE: the GEMM converts fp32->bf16 in-kernel while staging A,
// and the fused softmax+wmean reads ts directly. Saves the 50 MB Abf
// intermediate (write once + read twice) and the 151 MB convA stream.
#define BIAS_BLKS  (22 * 8)                          // 176
#define CONVW_BLKS (22 * 12)                         // 264 (64x64 tiles)
#define PREP_BLKS  (BIAS_BLKS + CONVW_BLKS)          // 440

__global__ __launch_bounds__(256) void prep_kernel(const float* __restrict__ text,
                                                   const float* __restrict__ anp,
                                                   const float* __restrict__ W11,
                                                   const float* __restrict__ b11,
                                                   const float* __restrict__ W12,
                                                   const float* __restrict__ b12,
                                                   unsigned short* __restrict__ Bt,
                                                   float* __restrict__ cbias) {
    const int blk = blockIdx.x;
    __shared__ float lds[64 * 65];         // transpose tile / bias reduce
    if (blk < BIAS_BLKS) {
        // c[b][n] = x_b @ Wcol_n + bias_n for 8 b x 64 n per block.
        const int c = blk >> 3;                      // chunk 0..21 (8 g-blocks share W)
        const int g = blk & 7;                       // b-group: b = g*8 + i
        const int w = threadIdx.x >> 6;              // k-slice 0..3
        const int l = threadIdx.x & 63;              // n-lane
        float acc[8] = {0.f, 0.f, 0.f, 0.f, 0.f, 0.f, 0.f, 0.f};
        int n;
        if (c < 12) {                                // h1 half: x=text, K=768
            n = c * 64 + l;
            const float* wcol = W11 + (size_t)T_DIM * H1_DIM + n;
            const int k0 = w * 192;
            #pragma unroll 4
            for (int k = k0; k < k0 + 192; ++k) {
                float wv = wcol[(size_t)k * H1_DIM];
                #pragma unroll
                for (int i = 0; i < 8; ++i)
                    acc[i] = fmaf(text[(g * 8 + i) * T_DIM + k], wv, acc[i]);
            }
        } else {                                     // h2 half: x=anp, K=512
            n = H1_DIM + (c - 12) * 64 + l;
            const float* wcol = W12 + (size_t)T_DIM * H2_DIM + (n - H1_DIM);
            const int k0 = w * 128;
            #pragma unroll 4
            for (int k = k0; k < k0 + 128; ++k) {
                float wv = wcol[(size_t)k * H2_DIM];
                #pragma unroll
                for (int i = 0; i < 8; ++i)
                    acc[i] = fmaf(anp[(g * 8 + i) * A_DIM + k], wv, acc[i]);
            }
        }
        #pragma unroll
        for (int i = 0; i < 8; ++i) lds[w * 512 + i * 64 + l] = acc[i];
        __syncthreads();
        const int i2 = threadIdx.x >> 6;             // 0..3; each thread 2 outputs
        const float base = (c < 12) ? b11[n] : b12[n - H1_DIM];
        #pragma unroll
        for (int rep = 0; rep < 2; ++rep) {
            const int i = i2 + rep * 4;
            float s = (lds[i * 64 + l] + lds[512 + i * 64 + l]) +
                      (lds[1024 + i * 64 + l] + lds[1536 + i * 64 + l]);
            cbias[(g * 8 + i) * N_DIM + n] = base + s;
        }
    } else {
        // convW: Bt[n][k] = bf16(W[k][n]) via 64x64 LDS transpose tile.
        const int t  = blk - BIAS_BLKS;
        const int nt = t / 12, kt = t % 12;          // n-tile 0..21, k-tile 0..11
        const int n0 = nt * 64, k0 = kt * 64;
        const int lo = threadIdx.x & 63;             // fast index
        const int hi = threadIdx.x >> 6;             // 0..3
        const float* Wp;  int ld;
        if (nt < 12) { Wp = W11 + n0;            ld = H1_DIM; }
        else         { Wp = W12 + (n0 - H1_DIM); ld = H2_DIM; }
        #pragma unroll
        for (int r = 0; r < 16; ++r) {
            int kl = hi * 16 + r;
            lds[kl * 65 + lo] = Wp[(size_t)(k0 + kl) * ld + lo];
        }
        __syncthreads();
        #pragma unroll
        for (int r = 0; r < 16; ++r) {
            int nl = hi * 16 + r;
            Bt[(size_t)(n0 + nl) * K_DIM + k0 + lo] = f2bf(lds[lo * 65 + nl]);
        }
    }
}

// --- main: bf16 MFMA GEMM, A staged fp32->bf16 IN-KERNEL from ts ---
// Proven r0 K-loop/reader/epilogue; only the A-staging changed:
// per K-tile each thread loads 8 coalesced float4 from ts, packs RNE bf16
// (bitwise == convA's f2bf), ds_write_b128 into the SAME swizzled layout
// gload_lds produced (content chunk c of row r at slot c^(r&7)).
// B-side gload_lds + source-swizzle unchanged; readers unchanged.
#define BM 128
#define BN 128
#define BK 64

__global__ __launch_bounds__(256, 3) void gemm_score_kernel(
        const float* __restrict__ ts,            // (M,K) fp32
        const unsigned short* __restrict__ Bt,   // (N,K) bf16
        const float* __restrict__ cbias,         // (B,N)
        const float* __restrict__ W21,           // (768)
        const float* __restrict__ W22,           // (640)
        float* __restrict__ part) {              // [22][B][S], one writer per slot
    __shared__ __align__(16) unsigned short As[BM * BK];   // 16 KB
    __shared__ __align__(16) unsigned short Bs[BN * BK];   // 16 KB
    const int tid  = threadIdx.x;
    const int lb   = blockIdx.x;
    const int xcd  = lb & 7;
    const int ib   = lb >> 3;                  // 0..351 per xcd
    const int m0   = ((ib / 11) * 8 + xcd) * BM;
    const int n0   = (ib % 11) * BN;
    const int lane = tid & 63;
    const int wave = tid >> 6;
    const int wm   = wave & 1;       // 2x2 waves over 128x128
    const int wn   = wave >> 1;
    const int quad = lane >> 4;
    const int col  = lane & 15;
    const int cswz = col & 7;        // row&7 == col&7 for fragment rows

    f32x4 acc[4][4] = {};            // 4x4 subtiles of 16x16 per wave

    // B staging geometry (unchanged): 8 rows x 64 k per instr, swizzled source
    const int wrow = lane >> 3;                        // 0..7 row within group
    const int kof  = (((lane & 7) ^ wrow) & 7) * 8;    // swizzled source chunk

    for (int k0 = 0; k0 < K_DIM; k0 += BK) {
        // A: 8 coalesced float4 loads (2 per chunk-slot, 4 slots/thread)
        float4 av[4][2];
        #pragma unroll
        for (int j = 0; j < 4; ++j) {
            const int c = tid + 256 * j;               // chunk-slot 0..1023
            const float4* src = (const float4*)(
                ts + (size_t)(m0 + (c >> 3)) * K_DIM + k0 + (c & 7) * 8);
            av[j][0] = src[0];
            av[j][1] = src[1];
        }
        // B: async global->LDS (unchanged)
        #pragma unroll
        for (int p = 0; p < 4; ++p) {
            const int r0 = p * 32 + wave * 8;
            __builtin_amdgcn_global_load_lds(
                (__attribute__((address_space(1))) void*)&Bt[(size_t)(n0 + r0 + wrow) * K_DIM + k0 + kof],
                (__attribute__((address_space(3))) void*)&Bs[r0 * BK],
                16, 0, 0);
        }
        // A: pack + swizzled ds_write_b128
        #pragma unroll
        for (int j = 0; j < 4; ++j) {
            const int c   = tid + 256 * j;
            const int row = c >> 3;
            const int cs  = (c & 7) ^ (row & 7);       // content chunk -> slot
            uint4 q;
            q.x = pk2(av[j][0].x, av[j][0].y);
            q.y = pk2(av[j][0].z, av[j][0].w);
            q.z = pk2(av[j][1].x, av[j][1].y);
            q.w = pk2(av[j][1].z, av[j][1].w);
            *(uint4*)&As[row * BK + cs * 8] = q;
        }
        __syncthreads();
        #pragma unroll
        for (int kk = 0; kk < BK; kk += 32) {
            s16x8 af[4], bf[4];
            const int ch = ((kk >> 3) + quad) ^ cswz;    // stored chunk index
            #pragma unroll
            for (int i = 0; i < 4; ++i)
                af[i] = *(const s16x8*)&As[(wm * 64 + i * 16 + col) * BK + ch * 8];
            #pragma unroll
            for (int j = 0; j < 4; ++j)
                bf[j] = *(const s16x8*)&Bs[(wn * 64 + j * 16 + col) * BK + ch * 8];
            #pragma unroll
            for (int i = 0; i < 4; ++i)
                #pragma unroll
                for (int j = 0; j < 4; ++j)
                    acc[i][j] = __builtin_amdgcn_mfma_f32_16x16x32_bf16(af[i], bf[j], acc[i][j], 0, 0, 0);
        }
        __syncthreads();
    }

    // Epilogue: part[slot][b][s] = sum over this wave's 64 n-cols of
    // tanh(acc + c[b][n]) * w2[n].  slot = jb*2 + wn; unique writer per slot.
    const int half = (n0 >= H1_DIM) ? 1 : 0;     // tiles never straddle halves
    const int jb   = n0 >> 7;                    // 0..10
    const float* w2p = half ? (W22 - H1_DIM) : W21;
    int   ncol[4];
    float w2v[4];
    #pragma unroll
    for (int j = 0; j < 4; ++j) {
        ncol[j] = n0 + wn * 64 + j * 16 + col;
        w2v[j]  = w2p[ncol[j]];
    }
    float* pc = part + (jb * 2 + wn) * M_DIM;
    #pragma unroll
    for (int i = 0; i < 4; ++i) {
        #pragma unroll
        for (int r = 0; r < 4; ++r) {
            int row_local = wm * 64 + i * 16 + quad * 4 + r;   // C/D: row=quad*4+reg
            int b = row_local & (B_DIM - 1);                   // m0 % 128 == 0
            int s = (m0 + row_local) >> 6;
            float v = 0.f;
            #pragma unroll
            for (int j = 0; j < 4; ++j) {
                float pre = acc[i][j][r] + cbias[b * N_DIM + ncol[j]];
                float ex  = __expf(2.f * pre);                 // tanh(x)=1-2/(e^{2x}+1)
                float th  = 1.f - 2.f * __builtin_amdgcn_rcpf(ex + 1.f);
                v = fmaf(th, w2v[j], v);
            }
            v += __shfl_xor(v, 1);    // reduce over the 16 cols (same quad = same row)
            v += __shfl_xor(v, 2);
            v += __shfl_xor(v, 4);
            v += __shfl_xor(v, 8);
            if (col == 0) pc[b * S_DIM + s] = v;
        }
    }
}

// --- fused softmax + weighted mean; atomic-free, reads ts fp32 directly ---
// grid (64 b, 12 t-chunks), 512 threads. Phase 1: softmax over S for this b
// (identical math to the old softmax kernel), result to LDS. 12x redundant
// per b but part is tiny and L3-hot. Phase 2: block owns an exclusive
// 64-t window -> direct stores, no atomics, no wsum buffer, no out-zeroing.
__global__ __launch_bounds__(512) void smwm_kernel(const float* __restrict__ part,
                                                   const float* __restrict__ ts,
                                                   float* __restrict__ out) {
    const int b  = blockIdx.x;
    const int tc = blockIdx.y;                   // t-chunk 0..11 (64 t each)
    __shared__ float wlds[512];
    __shared__ float redm[16], reds[16];
    __shared__ float acc2[1024];
    const int s = threadIdx.x;                   // 512 threads = 512 s
    float v0 = 0.f, v1 = 0.f;
    #pragma unroll
    for (int sl = 0; sl < 12; ++sl)       v0 += part[sl * M_DIM + b * S_DIM + s];
    #pragma unroll
    for (int sl = 12; sl < NSLOT; ++sl)   v1 += part[sl * M_DIM + b * S_DIM + s];
    float m0 = v0, m1 = v1;
    #pragma unroll
    for (int off = 32; off > 0; off >>= 1) {
        m0 = fmaxf(m0, __shfl_xor(m0, off));
        m1 = fmaxf(m1, __shfl_xor(m1, off));
    }
    const int w = s >> 6;
    if ((s & 63) == 0) { redm[w] = m0; redm[8 + w] = m1; }
    __syncthreads();
    m0 = redm[0]; m1 = redm[8];
    #pragma unroll
    for (int i = 1; i < 8; ++i) { m0 = fmaxf(m0, redm[i]); m1 = fmaxf(m1, redm[8 + i]); }
    float e0 = expf(v0 - m0), e1 = expf(v1 - m1);
    float s0 = e0, s1 = e1;
    #pragma unroll
    for (int off = 32; off > 0; off >>= 1) {
        s0 += __shfl_xor(s0, off);
        s1 += __shfl_xor(s1, off);
    }
    if ((s & 63) == 0) { reds[w] = s0; reds[8 + w] = s1; }
    __syncthreads();
    s0 = reds[0]; s1 = reds[8];
    #pragma unroll
    for (int i = 1; i < 8; ++i) { s0 += reds[i]; s1 += reds[8 + i]; }
    wlds[s] = e0 / s0 + e1 / s1;
    __syncthreads();

    // phase 2: out[b, tc*64 + tl] = (0.5/S) * sum_s wlds[s] * ts[s,b,t]
    const int tpl = threadIdx.x & 31;            // t-pair 0..31 within chunk
    const int ss  = threadIdx.x >> 5;            // s-strip 0..15
    const float* base = ts + (size_t)b * T_DIM + (tc * 32 + tpl) * 2;
    float a0 = 0.f, a1 = 0.f;
    #pragma unroll 4
    for (int i = 0; i < 32; ++i) {
        const int sv = ss + i * 16;
        const float2 u = *(const float2*)(base + (size_t)sv * (B_DIM * T_DIM));
        const float wv = wlds[sv];
        a0 = fmaf(wv, u.x, a0);
        a1 = fmaf(wv, u.y, a1);
    }
    acc2[ss * 64 + tpl * 2]     = a0;
    acc2[ss * 64 + tpl * 2 + 1] = a1;
    __syncthreads();
    if (threadIdx.x < 64) {
        float sum = 0.f;
        #pragma unroll
        for (int k = 0; k < 16; ++k) sum += acc2[k * 64 + threadIdx.x];
        out[b * T_DIM + tc * 64 + threadIdx.x] = sum * (0.5f / (float)S_DIM);
    }
}

extern "C" void kernel_launch(void* const* d_in, const int* in_sizes, int n_in,
                              void* d_out, int out_size, void* d_ws, size_t ws_size,
                              hipStream_t stream) {
    const float* text = (const float*)d_in[0];
    const float* anp  = (const float*)d_in[1];
    const float* ts   = (const float*)d_in[2];
    const float* W11  = (const float*)d_in[3];
    const float* b11  = (const float*)d_in[4];
    const float* W21  = (const float*)d_in[5];
    // d_in[6] = b21: unused, softmax is shift-invariant
    const float* W12  = (const float*)d_in[7];
    const float* b12  = (const float*)d_in[8];
    const float* W22  = (const float*)d_in[9];
    // d_in[10] = b22: unused
    float* out = (float*)d_out;

    // workspace layout (bytes): total ~5.4 MB (Abf eliminated)
    char* ws = (char*)d_ws;
    unsigned short* Bt  = (unsigned short*)ws;                 // 2162688 (1408x768 bf16)
    float* cbias = (float*)(ws + 2162688);                     //  360448 (64x1408 f32)
    float* part  = (float*)(ws + 2162688 + 360448);            // 2883584 (22x32768 f32)

    prep_kernel<<<PREP_BLKS, 256, 0, stream>>>(
        text, anp, W11, b11, W12, b12, Bt, cbias);
    gemm_score_kernel<<<(M_DIM / BM) * (N_DIM / BN), 256, 0, stream>>>(
        ts, Bt, cbias, W21, W22, part);
    smwm_kernel<<<dim3(B_DIM, 12), 512, 0, stream>>>(part, ts, out);
}

// Round 8
// 296.516 us; speedup vs baseline: 1.0964x; 1.0964x over previous
//
#include <hip/hip_runtime.h>
#include <stdint.h>

// Problem constants
#define S_DIM 512
#define B_DIM 64
#define T_DIM 768
#define A_DIM 512
#define H1_DIM 768
#define H2_DIM 640
#define N_DIM (H1_DIM + H2_DIM)   // 1408 combined hidden cols
#define M_DIM (S_DIM * B_DIM)     // 32768 rows
#define K_DIM T_DIM               // 768
#define NSLOT 22                  // 11 n-tiles x 2 wave-columns

typedef short s16x8 __attribute__((ext_vector_type(8)));
typedef float f32x4 __attribute__((ext_vector_type(4)));

__device__ __forceinline__ unsigned short f2bf(float f) {
    unsigned u = __float_as_uint(f);
    u += 0x7fffu + ((u >> 16) & 1u);   // round-to-nearest-even
    return (unsigned short)(u >> 16);
}

// --- fused prep: bias GEMV (blocked) | convW (LDS transpose) | convA ---
// convA restored (r7 lesson: in-GEMM A-staging costs +59 us vs gload_lds;
// materialized bf16 Abf feeds both GEMM and the smwm tail).
#define BIAS_BLKS  (22 * 8)                          // 176
#define CONVW_BLKS (22 * 12)                         // 264 (64x64 tiles)
#define CONVA_BLKS (M_DIM * K_DIM / 4 / 1024)        // 6144
#define PREP_BLKS  (BIAS_BLKS + CONVW_BLKS + CONVA_BLKS)

__global__ __launch_bounds__(256) void prep_kernel(const float* __restrict__ ts,
                                                   const float* __restrict__ text,
                                                   const float* __restrict__ anp,
                                                   const float* __restrict__ W11,
                                                   const float* __restrict__ b11,
                                                   const float* __restrict__ W12,
                                                   const float* __restrict__ b12,
                                                   unsigned short* __restrict__ Abf,
                                                   unsigned short* __restrict__ Bt,
                                                   float* __restrict__ cbias) {
    const int blk = blockIdx.x;
    __shared__ float lds[64 * 65];         // transpose tile / bias reduce
    if (blk < BIAS_BLKS) {
        // c[b][n] = x_b @ Wcol_n + bias_n for 8 b x 64 n per block.
        const int c = blk >> 3;                      // chunk 0..21 (8 g-blocks share W)
        const int g = blk & 7;                       // b-group: b = g*8 + i
        const int w = threadIdx.x >> 6;              // k-slice 0..3
        const int l = threadIdx.x & 63;              // n-lane
        float acc[8] = {0.f, 0.f, 0.f, 0.f, 0.f, 0.f, 0.f, 0.f};
        int n;
        if (c < 12) {                                // h1 half: x=text, K=768
            n = c * 64 + l;
            const float* wcol = W11 + (size_t)T_DIM * H1_DIM + n;
            const int k0 = w * 192;
            #pragma unroll 4
            for (int k = k0; k < k0 + 192; ++k) {
                float wv = wcol[(size_t)k * H1_DIM];
                #pragma unroll
                for (int i = 0; i < 8; ++i)
                    acc[i] = fmaf(text[(g * 8 + i) * T_DIM + k], wv, acc[i]);
            }
        } else {                                     // h2 half: x=anp, K=512
            n = H1_DIM + (c - 12) * 64 + l;
            const float* wcol = W12 + (size_t)T_DIM * H2_DIM + (n - H1_DIM);
            const int k0 = w * 128;
            #pragma unroll 4
            for (int k = k0; k < k0 + 128; ++k) {
                float wv = wcol[(size_t)k * H2_DIM];
                #pragma unroll
                for (int i = 0; i < 8; ++i)
                    acc[i] = fmaf(anp[(g * 8 + i) * A_DIM + k], wv, acc[i]);
            }
        }
        #pragma unroll
        for (int i = 0; i < 8; ++i) lds[w * 512 + i * 64 + l] = acc[i];
        __syncthreads();
        const int i2 = threadIdx.x >> 6;             // 0..3; each thread 2 outputs
        const float base = (c < 12) ? b11[n] : b12[n - H1_DIM];
        #pragma unroll
        for (int rep = 0; rep < 2; ++rep) {
            const int i = i2 + rep * 4;
            float s = (lds[i * 64 + l] + lds[512 + i * 64 + l]) +
                      (lds[1024 + i * 64 + l] + lds[1536 + i * 64 + l]);
            cbias[(g * 8 + i) * N_DIM + n] = base + s;
        }
    } else if (blk < BIAS_BLKS + CONVW_BLKS) {
        // convW: Bt[n][k] = bf16(W[k][n]) via 64x64 LDS transpose tile.
        const int t  = blk - BIAS_BLKS;
        const int nt = t / 12, kt = t % 12;          // n-tile 0..21, k-tile 0..11
        const int n0 = nt * 64, k0 = kt * 64;
        const int lo = threadIdx.x & 63;             // fast index
        const int hi = threadIdx.x >> 6;             // 0..3
        const float* Wp;  int ld;
        if (nt < 12) { Wp = W11 + n0;            ld = H1_DIM; }
        else         { Wp = W12 + (n0 - H1_DIM); ld = H2_DIM; }
        #pragma unroll
        for (int r = 0; r < 16; ++r) {
            int kl = hi * 16 + r;
            lds[kl * 65 + lo] = Wp[(size_t)(k0 + kl) * ld + lo];
        }
        __syncthreads();
        #pragma unroll
        for (int r = 0; r < 16; ++r) {
            int nl = hi * 16 + r;
            Bt[(size_t)(n0 + nl) * K_DIM + k0 + lo] = f2bf(lds[lo * 65 + nl]);
        }
    } else {
        // convA: text_seq fp32 -> bf16, 4 independent float4 loads per thread
        int i0 = (blk - BIAS_BLKS - CONVW_BLKS) * 1024 + threadIdx.x;
        float4 v0 = ((const float4*)ts)[i0];
        float4 v1 = ((const float4*)ts)[i0 + 256];
        float4 v2 = ((const float4*)ts)[i0 + 512];
        float4 v3 = ((const float4*)ts)[i0 + 768];
        ushort4 o0, o1, o2, o3;
        o0.x = f2bf(v0.x); o0.y = f2bf(v0.y); o0.z = f2bf(v0.z); o0.w = f2bf(v0.w);
        o1.x = f2bf(v1.x); o1.y = f2bf(v1.y); o1.z = f2bf(v1.z); o1.w = f2bf(v1.w);
        o2.x = f2bf(v2.x); o2.y = f2bf(v2.y); o2.z = f2bf(v2.z); o2.w = f2bf(v2.w);
        o3.x = f2bf(v3.x); o3.y = f2bf(v3.y); o3.z = f2bf(v3.z); o3.w = f2bf(v3.w);
        ((ushort4*)Abf)[i0]       = o0;
        ((ushort4*)Abf)[i0 + 256] = o1;
        ((ushort4*)Abf)[i0 + 512] = o2;
        ((ushort4*)Abf)[i0 + 768] = o3;
    }
}

// --- main: bf16 MFMA GEMM with fused tanh-dot epilogue -> part [22][B][S] ---
// Proven r0/r4 structure (89.5 us, 0 bank conflicts), byte-identical.
// LDS chunk swizzle: logical chunk c (16B) of row r stored at chunk c^(r&7)
// via the global_load_lds SOURCE address; readers XOR the same way.
// XCD-aware block swizzle: xcd = lb&7, i = lb>>3, m = (i/11)*8 + xcd, n = i%11.
#define BM 128
#define BN 128
#define BK 64

__global__ __launch_bounds__(256, 3) void gemm_score_kernel(
        const unsigned short* __restrict__ A,    // (M,K) bf16
        const unsigned short* __restrict__ Bt,   // (N,K) bf16
        const float* __restrict__ cbias,         // (B,N)
        const float* __restrict__ W21,           // (768)
        const float* __restrict__ W22,           // (640)
        float* __restrict__ part) {              // [22][B][S], one writer per slot
    __shared__ __align__(16) unsigned short As[BM * BK];   // 16 KB
    __shared__ __align__(16) unsigned short Bs[BN * BK];   // 16 KB
    const int tid  = threadIdx.x;
    const int lb   = blockIdx.x;
    const int xcd  = lb & 7;
    const int ib   = lb >> 3;                  // 0..351 per xcd
    const int m0   = ((ib / 11) * 8 + xcd) * BM;
    const int n0   = (ib % 11) * BN;
    const int lane = tid & 63;
    const int wave = tid >> 6;
    const int wm   = wave & 1;       // 2x2 waves over 128x128
    const int wn   = wave >> 1;
    const int quad = lane >> 4;
    const int col  = lane & 15;
    const int cswz = col & 7;        // row&7 == col&7 for fragment rows

    f32x4 acc[4][4] = {};            // 4x4 subtiles of 16x16 per wave

    // staging: each instr covers 8 rows x 64 k (1 KB contiguous LDS)
    const int wrow = lane >> 3;                        // 0..7 row within group
    const int kof  = (((lane & 7) ^ wrow) & 7) * 8;    // swizzled source chunk

    for (int k0 = 0; k0 < K_DIM; k0 += BK) {
        #pragma unroll
        for (int p = 0; p < 4; ++p) {
            const int r0 = p * 32 + wave * 8;    // wave-uniform row group (mult of 8)
            __builtin_amdgcn_global_load_lds(
                (__attribute__((address_space(1))) void*)&A[(size_t)(m0 + r0 + wrow) * K_DIM + k0 + kof],
                (__attribute__((address_space(3))) void*)&As[r0 * BK],
                16, 0, 0);
            __builtin_amdgcn_global_load_lds(
                (__attribute__((address_space(1))) void*)&Bt[(size_t)(n0 + r0 + wrow) * K_DIM + k0 + kof],
                (__attribute__((address_space(3))) void*)&Bs[r0 * BK],
                16, 0, 0);
        }
        __syncthreads();
        #pragma unroll
        for (int kk = 0; kk < BK; kk += 32) {
            s16x8 af[4], bf[4];
            const int ch = ((kk >> 3) + quad) ^ cswz;    // stored chunk index
            #pragma unroll
            for (int i = 0; i < 4; ++i)
                af[i] = *(const s16x8*)&As[(wm * 64 + i * 16 + col) * BK + ch * 8];
            #pragma unroll
            for (int j = 0; j < 4; ++j)
                bf[j] = *(const s16x8*)&Bs[(wn * 64 + j * 16 + col) * BK + ch * 8];
            #pragma unroll
            for (int i = 0; i < 4; ++i)
                #pragma unroll
                for (int j = 0; j < 4; ++j)
                    acc[i][j] = __builtin_amdgcn_mfma_f32_16x16x32_bf16(af[i], bf[j], acc[i][j], 0, 0, 0);
        }
        __syncthreads();
    }

    // Epilogue: part[slot][b][s] = sum over this wave's 64 n-cols of
    // tanh(acc + c[b][n]) * w2[n].  slot = jb*2 + wn; unique writer per slot.
    const int half = (n0 >= H1_DIM) ? 1 : 0;     // tiles never straddle halves
    const int jb   = n0 >> 7;                    // 0..10
    const float* w2p = half ? (W22 - H1_DIM) : W21;
    int   ncol[4];
    float w2v[4];
    #pragma unroll
    for (int j = 0; j < 4; ++j) {
        ncol[j] = n0 + wn * 64 + j * 16 + col;
        w2v[j]  = w2p[ncol[j]];
    }
    float* pc = part + (jb * 2 + wn) * M_DIM;
    #pragma unroll
    for (int i = 0; i < 4; ++i) {
        #pragma unroll
        for (int r = 0; r < 4; ++r) {
            int row_local = wm * 64 + i * 16 + quad * 4 + r;   // C/D: row=quad*4+reg
            int b = row_local & (B_DIM - 1);                   // m0 % 128 == 0
            int s = (m0 + row_local) >> 6;
            float v = 0.f;
            #pragma unroll
            for (int j = 0; j < 4; ++j) {
                float pre = acc[i][j][r] + cbias[b * N_DIM + ncol[j]];
                float ex  = __expf(2.f * pre);                 // tanh(x)=1-2/(e^{2x}+1)
                float th  = 1.f - 2.f * __builtin_amdgcn_rcpf(ex + 1.f);
                v = fmaf(th, w2v[j], v);
            }
            v += __shfl_xor(v, 1);    // reduce over the 16 cols (same quad = same row)
            v += __shfl_xor(v, 2);
            v += __shfl_xor(v, 4);
            v += __shfl_xor(v, 8);
            if (col == 0) pc[b * S_DIM + s] = v;
        }
    }
}

// --- fused softmax + weighted mean; atomic-free, reads Abf bf16 ---
// grid (64 b, 12 t-chunks), 512 threads. Phase 1: softmax over S for this b
// (identical math to the old softmax kernel), result to LDS. 12x redundant
// per b but part is tiny and L2/L3-hot. Phase 2: block owns an exclusive
// 64-t window -> direct stores, no atomics, no wsum buffer, no out-zeroing.
// Reads bf16 Abf (75 MB) not fp32 ts (151 MB).
__global__ __launch_bounds__(512) void smwm_kernel(const float* __restrict__ part,
                                                   const unsigned short* __restrict__ Abf,
                                                   float* __restrict__ out) {
    const int b  = blockIdx.x;
    const int tc = blockIdx.y;                   // t-chunk 0..11 (64 t each)
    __shared__ float wlds[512];
    __shared__ float redm[16], reds[16];
    __shared__ float acc2[1024];
    const int s = threadIdx.x;                   // 512 threads = 512 s
    float v0 = 0.f, v1 = 0.f;
    #pragma unroll
    for (int sl = 0; sl < 12; ++sl)       v0 += part[sl * M_DIM + b * S_DIM + s];
    #pragma unroll
    for (int sl = 12; sl < NSLOT; ++sl)   v1 += part[sl * M_DIM + b * S_DIM + s];
    float m0 = v0, m1 = v1;
    #pragma unroll
    for (int off = 32; off > 0; off >>= 1) {
        m0 = fmaxf(m0, __shfl_xor(m0, off));
        m1 = fmaxf(m1, __shfl_xor(m1, off));
    }
    const int w = s >> 6;
    if ((s & 63) == 0) { redm[w] = m0; redm[8 + w] = m1; }
    __syncthreads();
    m0 = redm[0]; m1 = redm[8];
    #pragma unroll
    for (int i = 1; i < 8; ++i) { m0 = fmaxf(m0, redm[i]); m1 = fmaxf(m1, redm[8 + i]); }
    float e0 = expf(v0 - m0), e1 = expf(v1 - m1);
    float s0 = e0, s1 = e1;
    #pragma unroll
    for (int off = 32; off > 0; off >>= 1) {
        s0 += __shfl_xor(s0, off);
        s1 += __shfl_xor(s1, off);
    }
    if ((s & 63) == 0) { reds[w] = s0; reds[8 + w] = s1; }
    __syncthreads();
    s0 = reds[0]; s1 = reds[8];
    #pragma unroll
    for (int i = 1; i < 8; ++i) { s0 += reds[i]; s1 += reds[8 + i]; }
    wlds[s] = e0 / s0 + e1 / s1;
    __syncthreads();

    // phase 2: out[b, tc*64 + tl] = (0.5/S) * sum_s wlds[s] * Abf[s,b,t]
    const int tpl = threadIdx.x & 31;            // t-pair 0..31 within chunk
    const int ss  = threadIdx.x >> 5;            // s-strip 0..15
    const unsigned short* base = Abf + (size_t)b * T_DIM + (tc * 32 + tpl) * 2;
    float a0 = 0.f, a1 = 0.f;
    #pragma unroll 4
    for (int i = 0; i < 32; ++i) {
        const int sv = ss + i * 16;
        const unsigned u = *(const unsigned*)(base + (size_t)sv * (B_DIM * T_DIM));
        const float wv = wlds[sv];
        a0 = fmaf(wv, __uint_as_float(u << 16),         a0);
        a1 = fmaf(wv, __uint_as_float(u & 0xffff0000u), a1);
    }
    acc2[ss * 64 + tpl * 2]     = a0;
    acc2[ss * 64 + tpl * 2 + 1] = a1;
    __syncthreads();
    if (threadIdx.x < 64) {
        float sum = 0.f;
        #pragma unroll
        for (int k = 0; k < 16; ++k) sum += acc2[k * 64 + threadIdx.x];
        out[b * T_DIM + tc * 64 + threadIdx.x] = sum * (0.5f / (float)S_DIM);
    }
}

extern "C" void kernel_launch(void* const* d_in, const int* in_sizes, int n_in,
                              void* d_out, int out_size, void* d_ws, size_t ws_size,
                              hipStream_t stream) {
    const float* text = (const float*)d_in[0];
    const float* anp  = (const float*)d_in[1];
    const float* ts   = (const float*)d_in[2];
    const float* W11  = (const float*)d_in[3];
    const float* b11  = (const float*)d_in[4];
    const float* W21  = (const float*)d_in[5];
    // d_in[6] = b21: unused, softmax is shift-invariant
    const float* W12  = (const float*)d_in[7];
    const float* b12  = (const float*)d_in[8];
    const float* W22  = (const float*)d_in[9];
    // d_in[10] = b22: unused
    float* out = (float*)d_out;

    // workspace layout (bytes): total ~55.7 MB
    char* ws = (char*)d_ws;
    unsigned short* Abf = (unsigned short*)ws;                       // 50331648
    unsigned short* Bt  = (unsigned short*)(ws + 50331648);          //  2162688
    float* cbias = (float*)(ws + 50331648 + 2162688);                //   360448
    float* part  = (float*)(ws + 50331648 + 2162688 + 360448);       //  2883584

    prep_kernel<<<PREP_BLKS, 256, 0, stream>>>(
        ts, text, anp, W11, b11, W12, b12, Abf, Bt, cbias);
    gemm_score_kernel<<<(M_DIM / BM) * (N_DIM / BN), 256, 0, stream>>>(
        Abf, Bt, cbias, W21, W22, part);
    smwm_kernel<<<dim3(B_DIM, 12), 512, 0, stream>>>(part, Abf, out);
}